// Round 2
// baseline (575.034 us; speedup 1.0000x reference)
//
#include <hip/hip_runtime.h>
#include <hip/hip_bf16.h>

typedef __bf16 bf16x8 __attribute__((ext_vector_type(8)));
typedef __bf16 bf16x4 __attribute__((ext_vector_type(4)));
typedef float  f32x4  __attribute__((ext_vector_type(4)));
typedef unsigned short u16;

#define S_TILE 8        // samples per workgroup tile
#define ROWS   128      // S_TILE * 16 nodes
#define XT_STRIDE 136   // row-dim stride of transposed X buffer (128 + 8 pad -> 2-way banks)
#define Z_STRIDE  136   // feat-dim stride of row-major Z buffer
#define P_STRIDE  264   // pooled feature stride (256 + 8)

// fixed 16-node graph: adjacency (incl. self-loops) as bitmasks, and degrees of A+I
__device__ const u16   g_adj[16] = {0x0133,0x0007,0x000E,0x000C,0x1131,0x0071,0x00E0,0x00C0,
                                    0x1311,0x0700,0x0E00,0x0C00,0x3110,0x7000,0xE000,0xC000};
__device__ const float g_deg[16] = {5,3,3,2,5,4,3,2,5,3,3,2,4,3,3,2};

__device__ __forceinline__ float elu_f(float x) {
    return x > 0.0f ? x : (__expf(x) - 1.0f);
}

// ---------------------------------------------------------------------------
// Pre-pack fp32 weights [K][N] into bf16 MFMA B-fragment-major layout:
//   out[((kt*NT + nt)*64 + lane)*8 + j] = bf16( W[kt*32 + (lane>>4)*8 + j][nt*16 + (lane&15)] )
// Packed offsets (elements): W1 @ 0 (8 frags), W2 @ 4096 (16), W3 @ 12288 (64), Wfc @ 45056 (128)
// ---------------------------------------------------------------------------
__global__ void prepack_kernel(const float* __restrict__ W1, const float* __restrict__ W2,
                               const float* __restrict__ W3, const float* __restrict__ Wfc,
                               __bf16* __restrict__ out)
{
    int t = blockIdx.x * blockDim.x + threadIdx.x;
    const float* W; int N; long obase;
    if      (t < 512)   { W = W1;  N = 64;  obase = 0;     }
    else if (t < 1536)  { W = W2;  N = 128; obase = 4096;  t -= 512;  }
    else if (t < 5632)  { W = W3;  N = 256; obase = 12288; t -= 1536; }
    else if (t < 13824) { W = Wfc; N = 256; obase = 45056; t -= 5632; }
    else return;
    const int frag = t >> 6;
    const int lane = t & 63;
    const int NT = N / 16;
    const int kt = frag / NT;
    const int nt = frag % NT;
    const int n  = nt * 16 + (lane & 15);
    const int k0 = kt * 32 + (lane >> 4) * 8;
    #pragma unroll
    for (int j = 0; j < 8; ++j)
        out[obase + ((long)frag * 64 + lane) * 8 + j] = (__bf16)W[(long)(k0 + j) * N + n];
}

// ---------------------------------------------------------------------------
// One GCN layer: X(row-major meaning, stored transposed sXT[feat][row])
//   Z = A_hat @ X   (computed transposed: Z^T = X^T @ A_hat^T, written row-major to sZ)
//   Y = Z @ W + b ; ELU -> back into sXT   (or max-pool over nodes -> sPool on last layer)
// Waves split the feature dimension; slices align between a layer's GEMM output
// and the next layer's aggregation input, so only 2 barriers per layer needed.
// ---------------------------------------------------------------------------
template<int FIN, int FOUT, bool LAST>
__device__ __forceinline__ void gcn_layer(u16* sXT, u16* sZ, u16* sPool,
                                          const __bf16* __restrict__ Wp,
                                          const float* __restrict__ bias,
                                          bf16x8 ahat, int lane, int wv)
{
    const int col = lane & 15;
    const int g   = lane >> 4;

    // ---- aggregation: Z^T = X^T * A_hat^T  (one MFMA per (feat-block, sample))
    constexpr int FBW = (FIN / 16) / 4;     // feat blocks per wave
    #pragma unroll
    for (int fbi = 0; fbi < FBW; ++fbi) {
        const int fb = wv * FBW + fbi;
        // A-operand rows = feats fb*16+col; k = node. Lanes g>=2 (k 16..31) have zero
        // A_hat coeffs; replicate-read valid rows ((g&1)*8) to avoid garbage*0=NaN.
        const u16* xbase = &sXT[(fb * 16 + col) * XT_STRIDE + (g & 1) * 8];
        #pragma unroll
        for (int s = 0; s < S_TILE; ++s) {
            bf16x8 a = *reinterpret_cast<const bf16x8*>(xbase + s * 16);
            f32x4 c = {0.f, 0.f, 0.f, 0.f};
            c = __builtin_amdgcn_mfma_f32_16x16x32_bf16(a, ahat, c, 0, 0, 0);
            // c[i] = Z^T[fb*16 + g*4 + i][node col] -> sZ[s*16+col][fb*16+g*4+i] (4 contiguous)
            bf16x4 zp;
            #pragma unroll
            for (int i = 0; i < 4; ++i) zp[i] = (__bf16)c[i];
            *reinterpret_cast<bf16x4*>(&sZ[(s * 16 + col) * Z_STRIDE + fb * 16 + g * 4]) = zp;
        }
    }
    __syncthreads();

    // ---- GEMM: Y = Z @ W (+ bias, ELU) -> sXT, or max-pool -> sPool
    constexpr int NT  = FOUT / 16;
    constexpr int KT  = FIN / 32;
    constexpr int NBW = NT / 4;
    #pragma unroll
    for (int nbi = 0; nbi < NBW; ++nbi) {
        const int nb = wv * NBW + nbi;
        bf16x8 bfr[KT];
        #pragma unroll
        for (int kt = 0; kt < KT; ++kt)
            bfr[kt] = *reinterpret_cast<const bf16x8*>(Wp + ((long)(kt * NT + nb) * 64 + lane) * 8);
        const float bv = bias[nb * 16 + col];
        #pragma unroll
        for (int s = 0; s < S_TILE; ++s) {
            f32x4 acc = {0.f, 0.f, 0.f, 0.f};
            #pragma unroll
            for (int kt = 0; kt < KT; ++kt) {
                bf16x8 a = *reinterpret_cast<const bf16x8*>(
                    &sZ[(s * 16 + col) * Z_STRIDE + kt * 32 + g * 8]);
                acc = __builtin_amdgcn_mfma_f32_16x16x32_bf16(a, bfr[kt], acc, 0, 0, 0);
            }
            if (!LAST) {
                // C layout: row = node g*4+i, col = feat nb*16+col.
                // Write transposed: 4 consecutive rows contiguous in sXT -> one b64.
                bf16x4 xp;
                #pragma unroll
                for (int i = 0; i < 4; ++i) xp[i] = (__bf16)elu_f(acc[i] + bv);
                *reinterpret_cast<bf16x4*>(&sXT[(nb * 16 + col) * XT_STRIDE + s * 16 + g * 4]) = xp;
            } else {
                // max over 16 nodes (bias/ELU commute with max): 4 local + cross-group shfl
                float m = fmaxf(fmaxf(acc[0], acc[1]), fmaxf(acc[2], acc[3]));
                m = fmaxf(m, __shfl_xor(m, 16));
                m = fmaxf(m, __shfl_xor(m, 32));
                m = elu_f(m + bv);
                if (g == 0) {
                    __bf16 h = (__bf16)m;
                    sPool[s * P_STRIDE + nb * 16 + col] = __builtin_bit_cast(u16, h);
                }
            }
        }
    }
    __syncthreads();
}

// ---------------------------------------------------------------------------
// Fused GCN: obs -> L1 -> L2 -> L3 -> maxpool -> FC -> out, one 8-sample tile per WG
// ---------------------------------------------------------------------------
__global__ __launch_bounds__(256, 2) void gcn_fused(
    const float* __restrict__ obs,
    const float* __restrict__ b1, const float* __restrict__ b2,
    const float* __restrict__ b3, const float* __restrict__ bfc,
    const __bf16* __restrict__ Wp, float* __restrict__ out)
{
    __shared__ u16 sXT[128 * XT_STRIDE];   // [feat<=128][row 0..127]  34 KiB
    __shared__ u16 sZ[ROWS * Z_STRIDE];    // [row][feat<=128]         34 KiB
    __shared__ u16 sPool[16 * P_STRIDE];   // [sample pad 16][256]     8.25 KiB

    const int tid  = threadIdx.x;
    const int lane = tid & 63;
    const int wv   = tid >> 6;
    const int col  = lane & 15;
    const int g    = lane >> 4;

    // constant A_hat^T B-fragment: B[k][n], n = col (out node), k = g*8+j (in node, 0 for k>=16)
    bf16x8 ahat;
    #pragma unroll
    for (int j = 0; j < 8; ++j) {
        const int k = g * 8 + j;
        float v = 0.f;
        if (k < 16 && ((g_adj[col] >> k) & 1)) v = rsqrtf(g_deg[col] * g_deg[k]);
        ahat[j] = (__bf16)v;
    }

    // ---- stage obs tile into sXT (transposed [feat][row]), packed b128 writes
    const long rowBase = (long)blockIdx.x * ROWS;
    const float* obs_t = obs + rowBase * 64;
    {
        const int q  = tid & 15;          // feature quad (feats 4q..4q+3)
        const int r0 = (tid >> 4) * 8;    // 8 consecutive rows
        float vals[4][8];
        #pragma unroll
        for (int i = 0; i < 8; ++i) {
            const float4 v = reinterpret_cast<const float4*>(obs_t)[(r0 + i) * 16 + q];
            vals[0][i] = v.x; vals[1][i] = v.y; vals[2][i] = v.z; vals[3][i] = v.w;
        }
        #pragma unroll
        for (int f = 0; f < 4; ++f) {
            bf16x8 p;
            #pragma unroll
            for (int i = 0; i < 8; ++i) p[i] = (__bf16)vals[f][i];
            *reinterpret_cast<bf16x8*>(&sXT[(q * 4 + f) * XT_STRIDE + r0]) = p;
        }
    }
    __syncthreads();

    gcn_layer< 64,  64, false>(sXT, sZ, sPool, Wp + 0,     b1, ahat, lane, wv);
    gcn_layer< 64, 128, false>(sXT, sZ, sPool, Wp + 4096,  b2, ahat, lane, wv);
    gcn_layer<128, 256, true >(sXT, sZ, sPool, Wp + 12288, b3, ahat, lane, wv);

    // ---- FC: out = ELU(pooled @ Wfc + bfc). Pooled rows 8..15 are garbage but
    // MFMA rows are independent; we only store rows 0..7 (groups g<2).
    const __bf16* Wf = Wp + 45056;
    bf16x8 afc[8];
    #pragma unroll
    for (int kt = 0; kt < 8; ++kt)
        afc[kt] = *reinterpret_cast<const bf16x8*>(&sPool[col * P_STRIDE + kt * 32 + g * 8]);
    const long sampleBase = (long)blockIdx.x * S_TILE;
    #pragma unroll
    for (int nbi = 0; nbi < 4; ++nbi) {
        const int nb = wv * 4 + nbi;
        f32x4 acc = {0.f, 0.f, 0.f, 0.f};
        #pragma unroll
        for (int kt = 0; kt < 8; ++kt) {
            bf16x8 b = *reinterpret_cast<const bf16x8*>(Wf + ((long)(kt * 16 + nb) * 64 + lane) * 8);
            acc = __builtin_amdgcn_mfma_f32_16x16x32_bf16(afc[kt], b, acc, 0, 0, 0);
        }
        const float bv = bfc[nb * 16 + col];
        if (g < 2) {
            #pragma unroll
            for (int i = 0; i < 4; ++i)
                out[(sampleBase + g * 4 + i) * 256 + nb * 16 + col] = elu_f(acc[i] + bv);
        }
    }
}

extern "C" void kernel_launch(void* const* d_in, const int* in_sizes, int n_in,
                              void* d_out, int out_size, void* d_ws, size_t ws_size,
                              hipStream_t stream) {
    const float* obs = (const float*)d_in[0];
    const float* W1  = (const float*)d_in[1];
    const float* b1  = (const float*)d_in[2];
    const float* W2  = (const float*)d_in[3];
    const float* b2  = (const float*)d_in[4];
    const float* W3  = (const float*)d_in[5];
    const float* b3  = (const float*)d_in[6];
    const float* Wfc = (const float*)d_in[7];
    const float* bfc = (const float*)d_in[8];
    __bf16* Wp = (__bf16*)d_ws;              // 110592 bf16 = 216 KiB packed weights
    float* out = (float*)d_out;

    const int B = in_sizes[0] / (16 * 64);   // 65536
    prepack_kernel<<<dim3(54), dim3(256), 0, stream>>>(W1, W2, W3, Wfc, Wp);
    gcn_fused<<<dim3(B / S_TILE), dim3(256), 0, stream>>>(obs, b1, b2, b3, bfc, Wp, out);
}

// Round 3
// 553.367 us; speedup vs baseline: 1.0392x; 1.0392x over previous
//
#include <hip/hip_runtime.h>
#include <hip/hip_bf16.h>

typedef __bf16 bf16x8 __attribute__((ext_vector_type(8)));
typedef __bf16 bf16x4 __attribute__((ext_vector_type(4)));
typedef float  f32x4  __attribute__((ext_vector_type(4)));
typedef unsigned short u16;

#define S_TILE 4        // samples per workgroup tile
#define ROWS   64       // S_TILE * 16 nodes
#define P_STRIDE 264    // pooled feature stride (256 + 8)

// LDS layouts (XOR-swizzled 8-element/16B granules, power-of-2 strides, no pad):
//   sXT [feat][row64]: idx = f*64 + ((r>>3) ^ (f&7))*8 + (r&7)      (16 KiB @128 feats)
//   sZ  [row64][feat]: idx = r*128 + (((f>>3) ^ (r&7))*8) + (f&7)   (16 KiB @128 feats)
// Swizzle spreads the (stride ≡ 0 mod 32 dwords) accesses across bank quads.

// fixed 16-node graph: adjacency (incl. self-loops) as bitmasks, and degrees of A+I
__device__ const u16   g_adj[16] = {0x0133,0x0007,0x000E,0x000C,0x1131,0x0071,0x00E0,0x00C0,
                                    0x1311,0x0700,0x0E00,0x0C00,0x3110,0x7000,0xE000,0xC000};
__device__ const float g_deg[16] = {5,3,3,2,5,4,3,2,5,3,3,2,4,3,3,2};

__device__ __forceinline__ float elu_f(float x) {
    return x > 0.0f ? x : (__expf(x) - 1.0f);
}

// ---------------------------------------------------------------------------
// Pre-pack fp32 weights [K][N] into bf16 MFMA B-fragment-major layout:
//   out[((kt*NT + nt)*64 + lane)*8 + j] = bf16( W[kt*32 + (lane>>4)*8 + j][nt*16 + (lane&15)] )
// Packed offsets (elements): W1 @ 0 (8 frags), W2 @ 4096 (16), W3 @ 12288 (64), Wfc @ 45056 (128)
// ---------------------------------------------------------------------------
__global__ void prepack_kernel(const float* __restrict__ W1, const float* __restrict__ W2,
                               const float* __restrict__ W3, const float* __restrict__ Wfc,
                               __bf16* __restrict__ out)
{
    int t = blockIdx.x * blockDim.x + threadIdx.x;
    const float* W; int N; long obase;
    if      (t < 512)   { W = W1;  N = 64;  obase = 0;     }
    else if (t < 1536)  { W = W2;  N = 128; obase = 4096;  t -= 512;  }
    else if (t < 5632)  { W = W3;  N = 256; obase = 12288; t -= 1536; }
    else if (t < 13824) { W = Wfc; N = 256; obase = 45056; t -= 5632; }
    else return;
    const int frag = t >> 6;
    const int lane = t & 63;
    const int NT = N / 16;
    const int kt = frag / NT;
    const int nt = frag % NT;
    const int n  = nt * 16 + (lane & 15);
    const int k0 = kt * 32 + (lane >> 4) * 8;
    #pragma unroll
    for (int j = 0; j < 8; ++j)
        out[obase + ((long)frag * 64 + lane) * 8 + j] = (__bf16)W[(long)(k0 + j) * N + n];
}

// ---------------------------------------------------------------------------
// One GCN layer: sXT[feat][row] -> (aggregate) sZ[row][feat] -> (GEMM+bias+ELU)
// back into sXT, or max-pool into sPool on the last layer.
// GEMM holds all A-fragments in registers (loaded once) and streams B from
// global (L2-resident packed weights) — cuts L3 LDS reads 4x vs per-nbi reload.
// ---------------------------------------------------------------------------
template<int FIN, int FOUT, bool LAST>
__device__ __forceinline__ void gcn_layer(u16* sXT, u16* sZ, u16* sPool,
                                          const __bf16* __restrict__ Wp,
                                          const float* __restrict__ bias,
                                          bf16x8 ahat, int lane, int wv)
{
    const int col = lane & 15;
    const int g   = lane >> 4;
    const int c7  = col & 7;

    // ---- aggregation: Z^T = X^T * A_hat^T  (one MFMA per (feat-block, sample))
    constexpr int FBW = (FIN / 16) / 4;     // feat blocks per wave
    #pragma unroll
    for (int fbi = 0; fbi < FBW; ++fbi) {
        const int fb = wv * FBW + fbi;
        const int f  = fb * 16 + col;       // A-row feat; f&7 == col&7
        #pragma unroll
        for (int s = 0; s < S_TILE; ++s) {
            // lanes g>=2 are k=16..31 (zero A_hat coeffs); replicate-read (g&1) granule
            const int gr = ((s * 2 + (g & 1)) ^ c7);
            bf16x8 a = *reinterpret_cast<const bf16x8*>(&sXT[f * 64 + gr * 8]);
            f32x4 c = {0.f, 0.f, 0.f, 0.f};
            c = __builtin_amdgcn_mfma_f32_16x16x32_bf16(a, ahat, c, 0, 0, 0);
            // c[i] = Z[row = s*16+col][feat fb*16 + g*4 + i] -> b64 write
            const int r   = s * 16 + col;
            const int zgr = ((fb * 2 + (g >> 1)) ^ c7);
            bf16x4 zp;
            #pragma unroll
            for (int i = 0; i < 4; ++i) zp[i] = (__bf16)c[i];
            *reinterpret_cast<bf16x4*>(&sZ[r * 128 + zgr * 8 + (g & 1) * 4]) = zp;
        }
    }
    __syncthreads();

    // ---- GEMM: Y = Z @ W (+ bias, ELU) -> sXT, or max-pool -> sPool
    constexpr int NT  = FOUT / 16;
    constexpr int KT  = FIN / 32;
    constexpr int NBW = NT / 4;
    bf16x8 afr[S_TILE][KT];                 // all A-frags, loaded once
    #pragma unroll
    for (int s = 0; s < S_TILE; ++s) {
        const int r = s * 16 + col;
        #pragma unroll
        for (int kt = 0; kt < KT; ++kt) {
            const int gr = ((kt * 4 + g) ^ c7);
            afr[s][kt] = *reinterpret_cast<const bf16x8*>(&sZ[r * 128 + gr * 8]);
        }
    }
    #pragma unroll
    for (int nbi = 0; nbi < NBW; ++nbi) {
        const int nb = wv * NBW + nbi;
        bf16x8 bfr[KT];
        #pragma unroll
        for (int kt = 0; kt < KT; ++kt)
            bfr[kt] = *reinterpret_cast<const bf16x8*>(Wp + ((long)(kt * NT + nb) * 64 + lane) * 8);
        const float bv = bias[nb * 16 + col];
        #pragma unroll
        for (int s = 0; s < S_TILE; ++s) {
            f32x4 acc = {0.f, 0.f, 0.f, 0.f};
            #pragma unroll
            for (int kt = 0; kt < KT; ++kt)
                acc = __builtin_amdgcn_mfma_f32_16x16x32_bf16(afr[s][kt], bfr[kt], acc, 0, 0, 0);
            if (!LAST) {
                // acc[i] = Y[node g*4+i][feat nb*16+col]; write transposed b64 into sXT
                const int f   = nb * 16 + col;
                const int xgr = ((s * 2 + (g >> 1)) ^ c7);
                bf16x4 xp;
                #pragma unroll
                for (int i = 0; i < 4; ++i) xp[i] = (__bf16)elu_f(acc[i] + bv);
                *reinterpret_cast<bf16x4*>(&sXT[f * 64 + xgr * 8 + (g & 1) * 4]) = xp;
            } else {
                // max over 16 nodes (bias/ELU commute with max): 4 local + cross-group shfl
                float m = fmaxf(fmaxf(acc[0], acc[1]), fmaxf(acc[2], acc[3]));
                m = fmaxf(m, __shfl_xor(m, 16));
                m = fmaxf(m, __shfl_xor(m, 32));
                m = elu_f(m + bv);
                if (g == 0) {
                    __bf16 h = (__bf16)m;
                    sPool[s * P_STRIDE + nb * 16 + col] = __builtin_bit_cast(u16, h);
                }
            }
        }
    }
    __syncthreads();
}

// ---------------------------------------------------------------------------
// Fused GCN: obs -> L1 -> L2 -> L3 -> maxpool -> FC -> out, one 4-sample tile per WG
// ---------------------------------------------------------------------------
__global__ __launch_bounds__(256, 4) void gcn_fused(
    const float* __restrict__ obs,
    const float* __restrict__ b1, const float* __restrict__ b2,
    const float* __restrict__ b3, const float* __restrict__ bfc,
    const __bf16* __restrict__ Wp, float* __restrict__ out)
{
    __shared__ u16 sXT[128 * 64];          // [feat][row]  16 KiB
    __shared__ u16 sZ[ROWS * 128];         // [row][feat]  16 KiB
    __shared__ u16 sPool[S_TILE * P_STRIDE]; // 2.06 KiB

    const int tid  = threadIdx.x;
    const int lane = tid & 63;
    const int wv   = tid >> 6;
    const int col  = lane & 15;
    const int g    = lane >> 4;

    // constant A_hat^T B-fragment: B[k][n], n = col (out node), k = g*8+j (in node, 0 for k>=16)
    bf16x8 ahat;
    #pragma unroll
    for (int j = 0; j < 8; ++j) {
        const int k = g * 8 + j;
        float v = 0.f;
        if (k < 16 && ((g_adj[col] >> k) & 1)) v = rsqrtf(g_deg[col] * g_deg[k]);
        ahat[j] = (__bf16)v;
    }

    // ---- stage obs tile into sXT (transposed [feat][row]), swizzled b64 writes
    const long rowBase = (long)blockIdx.x * ROWS;
    const float* obs_t = obs + rowBase * 64;
    {
        const int q   = tid & 15;           // feature quad (feats 4q..4q+3)
        const int rg  = (tid >> 4) & 7;     // row granule (8 rows)
        const int dup = tid >> 7;           // which half of the granule (4 rows)
        const int r0  = rg * 8 + dup * 4;
        float vals[4][4];
        #pragma unroll
        for (int i = 0; i < 4; ++i) {
            const float4 v = reinterpret_cast<const float4*>(obs_t)[(r0 + i) * 16 + q];
            vals[0][i] = v.x; vals[1][i] = v.y; vals[2][i] = v.z; vals[3][i] = v.w;
        }
        #pragma unroll
        for (int f = 0; f < 4; ++f) {
            const int feat = q * 4 + f;
            const int gr   = rg ^ (feat & 7);
            bf16x4 p;
            #pragma unroll
            for (int i = 0; i < 4; ++i) p[i] = (__bf16)vals[f][i];
            *reinterpret_cast<bf16x4*>(&sXT[feat * 64 + gr * 8 + dup * 4]) = p;
        }
    }
    __syncthreads();

    gcn_layer< 64,  64, false>(sXT, sZ, sPool, Wp + 0,     b1, ahat, lane, wv);
    gcn_layer< 64, 128, false>(sXT, sZ, sPool, Wp + 4096,  b2, ahat, lane, wv);
    gcn_layer<128, 256, true >(sXT, sZ, sPool, Wp + 12288, b3, ahat, lane, wv);

    // ---- FC: out = ELU(pooled @ Wfc + bfc). Replicate-read samples (col&3) so
    // all A rows are valid; only C rows 0..3 (g==0) are stored.
    const __bf16* Wf = Wp + 45056;
    bf16x8 afc[8];
    #pragma unroll
    for (int kt = 0; kt < 8; ++kt)
        afc[kt] = *reinterpret_cast<const bf16x8*>(&sPool[(col & 3) * P_STRIDE + kt * 32 + g * 8]);
    const long sampleBase = (long)blockIdx.x * S_TILE;
    #pragma unroll
    for (int nbi = 0; nbi < 4; ++nbi) {
        const int nb = wv * 4 + nbi;
        f32x4 acc = {0.f, 0.f, 0.f, 0.f};
        #pragma unroll
        for (int kt = 0; kt < 8; ++kt) {
            bf16x8 b = *reinterpret_cast<const bf16x8*>(Wf + ((long)(kt * 16 + nb) * 64 + lane) * 8);
            acc = __builtin_amdgcn_mfma_f32_16x16x32_bf16(afc[kt], b, acc, 0, 0, 0);
        }
        const float bv = bfc[nb * 16 + col];
        if (g == 0) {
            #pragma unroll
            for (int i = 0; i < 4; ++i)
                out[(sampleBase + i) * 256 + nb * 16 + col] = elu_f(acc[i] + bv);
        }
    }
}

extern "C" void kernel_launch(void* const* d_in, const int* in_sizes, int n_in,
                              void* d_out, int out_size, void* d_ws, size_t ws_size,
                              hipStream_t stream) {
    const float* obs = (const float*)d_in[0];
    const float* W1  = (const float*)d_in[1];
    const float* b1  = (const float*)d_in[2];
    const float* W2  = (const float*)d_in[3];
    const float* b2  = (const float*)d_in[4];
    const float* W3  = (const float*)d_in[5];
    const float* b3  = (const float*)d_in[6];
    const float* Wfc = (const float*)d_in[7];
    const float* bfc = (const float*)d_in[8];
    __bf16* Wp = (__bf16*)d_ws;              // 110592 bf16 = 216 KiB packed weights
    float* out = (float*)d_out;

    const int B = in_sizes[0] / (16 * 64);   // 65536
    prepack_kernel<<<dim3(54), dim3(256), 0, stream>>>(W1, W2, W3, Wfc, Wp);
    gcn_fused<<<dim3(B / S_TILE), dim3(256), 0, stream>>>(obs, b1, b2, b3, bfc, Wp, out);
}